// Round 11
// baseline (2056.249 us; speedup 1.0000x reference)
//
#include <hip/hip_runtime.h>
#include <cstdint>
#include <cstddef>
#include <cstring>

#define LSEQ 512
#define BATCH 64
#define DIM 256
#define HID 256
#define NTAG 11

typedef float vf4 __attribute__((ext_vector_type(4)));
typedef __bf16 bf16x8 __attribute__((ext_vector_type(8)));
typedef float f32x4 __attribute__((ext_vector_type(4)));
typedef _Float16 h2 __attribute__((ext_vector_type(2)));
typedef unsigned short u16;

static __device__ __forceinline__ float dot2_f16(unsigned int w, unsigned int h, float acc)
{
#if __has_builtin(__builtin_amdgcn_fdot2)
    return __builtin_amdgcn_fdot2(__builtin_bit_cast(h2, w),
                                  __builtin_bit_cast(h2, h), acc, false);
#else
    h2 a = __builtin_bit_cast(h2, w), b = __builtin_bit_cast(h2, h);
    acc = fmaf((float)a.x, (float)b.x, acc);
    return fmaf((float)a.y, (float)b.y, acc);
#endif
}

// Fast transcendentals on the serial critical path (r10: -118us verified).
static __device__ __forceinline__ float fast_sig(float x)
{
#if __has_builtin(__builtin_amdgcn_exp2f) && __has_builtin(__builtin_amdgcn_rcpf)
    return __builtin_amdgcn_rcpf(1.f + __builtin_amdgcn_exp2f(x * -1.442695041f));
#else
    return 1.f / (1.f + expf(-x));
#endif
}
static __device__ __forceinline__ float fast_tanh(float x)
{
#if __has_builtin(__builtin_amdgcn_exp2f) && __has_builtin(__builtin_amdgcn_rcpf)
    return 1.f - 2.f * __builtin_amdgcn_rcpf(__builtin_amdgcn_exp2f(x * 2.885390082f) + 1.f);
#else
    return tanhf(x);
#endif
}

// 16B coherent load: sc0 sc1 bypasses L1/L2 so remote-XCD publishes are
// visible; reads the L3/MALL ordering point directly.
static __device__ __forceinline__ uint4 poll_load16(const unsigned int* p)
{
    uint4 v;
    asm volatile("global_load_dwordx4 %0, %1, off sc0 sc1\n"
                 "s_waitcnt vmcnt(0)"
                 : "=&v"(v) : "v"(p) : "memory");
    return v;
}

// ---------------- fp32 -> bf16 (RNE) convert ----------------
__global__ void __launch_bounds__(256) cvt_bf16(
    const float* __restrict__ src, u16* __restrict__ dst, int n4)
{
    int i = blockIdx.x * blockDim.x + threadIdx.x;
    const int stride = gridDim.x * blockDim.x;
    for (; i < n4; i += stride) {
        float4 f = ((const float4*)src)[i];
        ushort4 r;
        unsigned int u;
        u = __float_as_uint(f.x); u += 0x7FFFu + ((u >> 16) & 1u); r.x = (u16)(u >> 16);
        u = __float_as_uint(f.y); u += 0x7FFFu + ((u >> 16) & 1u); r.y = (u16)(u >> 16);
        u = __float_as_uint(f.z); u += 0x7FFFu + ((u >> 16) & 1u); r.z = (u16)(u >> 16);
        u = __float_as_uint(f.w); u += 0x7FFFu + ((u >> 16) & 1u); r.w = (u16)(u >> 16);
        ((ushort4*)dst)[i] = r;
    }
}

// ---------------- fp32 -> fp16 (RNE) convert ----------------
__global__ void __launch_bounds__(256) cvt_f16(
    const float* __restrict__ src, u16* __restrict__ dst, int n4)
{
    int i = blockIdx.x * blockDim.x + threadIdx.x;
    const int stride = gridDim.x * blockDim.x;
    for (; i < n4; i += stride) {
        float4 f = ((const float4*)src)[i];
        ushort4 r;
        r.x = __builtin_bit_cast(u16, (_Float16)f.x);
        r.y = __builtin_bit_cast(u16, (_Float16)f.y);
        r.z = __builtin_bit_cast(u16, (_Float16)f.z);
        r.w = __builtin_bit_cast(u16, (_Float16)f.w);
        ((ushort4*)dst)[i] = r;
    }
}

// ---------------- input GEMM via bf16 MFMA (+gather, +bias) ----------------
// r11 restructure: FULL K=256 resident in LDS (two 128x264 u16 tiles,
// 135KB).  One load phase + ONE barrier replaces 16 barriers of 32-wide
// k-chunks; 512 MFMA/WG run uninterrupted.  Epilogue (gate-contiguous
// fp16 Gin) unchanged:
//   u16 index (((dir*CT + tl)*64 + b)*256 + e)*4 + q    (n = q*256 + e)
__global__ void __launch_bounds__(256) gemm_in(
    const int* __restrict__ sent, const u16* __restrict__ embb,
    const u16* __restrict__ w16f, const u16* __restrict__ w16b,
    const float* __restrict__ bf_, const float* __restrict__ bb_,
    u16* __restrict__ Gin, int t0, int CT)
{
    const int mtile = blockIdx.x, ntile = blockIdx.y, dir = blockIdx.z;
    const u16* __restrict__ W16 = dir ? w16b : w16f;
    const float* __restrict__ bias = dir ? bb_ : bf_;
    const int tid = threadIdx.x;
    const int wave = tid >> 6, lane = tid & 63;
    const int wm = wave & 1, wn = wave >> 1;

    __shared__ u16 Asm[128][264];   // [m][k], full K, pitch 264
    __shared__ u16 Bsm[128][264];   // [n][k]

    // staging: thread (row = tid>>1, half = tid&1) loads 128 u16 = 16 uint4
    const int row = tid >> 1, half = tid & 1;
    const u16* ap;
    {
        int m_g = mtile * 128 + row;
        int tl = m_g >> 6, b = m_g & 63;
        int tg = t0 + tl;
        int tt = dir ? (LSEQ - 1 - tg) : tg;
        ap = embb + (size_t)sent[b * LSEQ + tt] * DIM;
    }
    const u16* bp = W16 + (size_t)(ntile * 128 + row) * DIM;

#pragma unroll
    for (int j = 0; j < 16; j++) {
        *(uint4*)&Asm[row][half * 128 + j * 8] =
            *(const uint4*)(ap + half * 128 + j * 8);
        *(uint4*)&Bsm[row][half * 128 + j * 8] =
            *(const uint4*)(bp + half * 128 + j * 8);
    }
    __syncthreads();

    f32x4 acc[4][4];
#pragma unroll
    for (int i = 0; i < 4; i++)
#pragma unroll
        for (int j = 0; j < 4; j++) acc[i][j] = (f32x4){0.f, 0.f, 0.f, 0.f};

    const int col = lane & 15, quad = lane >> 4;

#pragma unroll
    for (int ki = 0; ki < 8; ki++) {
        const int k0 = ki * 32;
        bf16x8 af[4], bg[4];
#pragma unroll
        for (int i = 0; i < 4; i++) {
            af[i] = *(const bf16x8*)&Asm[wm * 64 + i * 16 + col][k0 + quad * 8];
            bg[i] = *(const bf16x8*)&Bsm[wn * 64 + i * 16 + col][k0 + quad * 8];
        }
#pragma unroll
        for (int mt = 0; mt < 4; mt++)
#pragma unroll
            for (int nt = 0; nt < 4; nt++)
                acc[mt][nt] = __builtin_amdgcn_mfma_f32_16x16x32_bf16(
                    af[mt], bg[nt], acc[mt][nt], 0, 0, 0);
    }

#pragma unroll
    for (int nt = 0; nt < 4; nt++) {
        const int n_g = ntile * 128 + wn * 64 + nt * 16 + col;
        const float bv = bias[n_g];
        const int q = n_g >> 8, e = n_g & 255;
#pragma unroll
        for (int mt = 0; mt < 4; mt++)
#pragma unroll
            for (int r = 0; r < 4; r++) {
                const int m_g = mtile * 128 + wm * 64 + mt * 16 + quad * 4 + r;
                const int tl = m_g >> 6, b = m_g & 63;
                Gin[(((size_t)(dir * CT + tl) * 64 + b) * 256 + e) * 4 + q]
                    = __builtin_bit_cast(u16, (_Float16)(acc[mt][nt][r] + bv));
            }
    }
}

// ---------------- persistent bidirectional LSTM recurrence ------
// r11: COUNTER-GATED exchange replaces tag-in-data polling.
//  - publishers store untagged fp16 payload (u32, relaxed agent) to hdat;
//  - after a wave's stores retire (s_waitcnt vmcnt(0) is WAVE-wide), lane 0
//    bumps the per-(group,member) counter (+1/wave, +4/member/step);
//  - consumers poll ONLY the 8 member counters (two dwordx4, SAME address
//    across all lanes => 1 broadcast request/wave/iter vs 64 lanes x 16B
//    of distinct htag words before) until all >= 4t, then read payload
//    ONCE.  Poll L3 traffic drops ~30x; per-step discovery becomes a
//    single event per member instead of max-over-128-words.
// Liveness: increment precedes the member's own next poll (no circular
// wait); ">=" on monotonic counters cannot hang on stale values; hcnt is
// zeroed by hipMemsetAsync each launch.  Slot-overwrite safety: member
// overwrites slot k&1 only after counters>=4k => every reader finished
// its iteration-(k-1) staging read of that slot (same induction as the
// proven tag scheme).
// Structure otherwise = r10: 256 WGs = 32 groups x 8 members; fp16 dot2
// GEMV from thread-private LDS weight blocks (pitch 65); reduce-scatter
// over lane^{1,2,4,8}; fast_sig/fast_tanh cell; fp16 Gin CT=512.
__global__ void __launch_bounds__(256, 1) lstm_rec(
    const u16* __restrict__ Gin,
    const u16* __restrict__ Whh16f, const u16* __restrict__ Whh16b,
    const float* __restrict__ h0, const float* __restrict__ c0,
    float* __restrict__ hs, unsigned int* __restrict__ hdat,
    unsigned int* __restrict__ hcnt, float* __restrict__ cbuf,
    int t0, int CT)
{
    const int wg = blockIdx.x;
    const int w = wg >> 5, g = wg & 31;
    const int dir   = g >> 4;
    const int bbase = (g & 15) << 2;
    const int tid = threadIdx.x;
    const int ks = tid & 15;            // k-slice index (16 halves = 8 dwords)
    const int ep = tid >> 4;            // ee-pair index 0..15
    const int ebase = w * 32 + ep * 2;  // first of the 2 hidden elems
    const int P0 = ks & 1, P1 = (ks >> 1) & 1, P2 = (ks >> 2) & 1;
    const int bloc = ks & 3;            // batch slot this thread finalizes
    const int e2sel = P2;               // which of its 2 elems it finalizes
    const u16* __restrict__ Whh16 = dir ? Whh16b : Whh16f;

    __shared__ unsigned int Wl[256 * 65];        // 66,560 B private blocks
    __shared__ unsigned int Hd[2][4][132];       // fp16-pair h, 4,224 B

    const int wbase = tid * 65;

    // ---- one-time weight stage into thread-private LDS block ----
#pragma unroll
    for (int e2 = 0; e2 < 2; e2++)
#pragma unroll
        for (int q = 0; q < 4; q++) {
            const unsigned int* wp =
                (const unsigned int*)(Whh16 + (size_t)(q * 256 + ebase + e2) * HID);
#pragma unroll
            for (int j = 0; j < 2; j++) {
                *(uint4*)&Wl[wbase + ((e2 * 4 + q) * 2 + j) * 4] =
                    *(const uint4*)(wp + 8 * ks + 4 * j);
            }
        }

    float c = ((t0 == 0) ? c0 : cbuf)
        [((size_t)dir * BATCH + bbase + bloc) * HID + ebase + e2sel];

    const int sb = tid >> 6, k4 = tid & 63;   // staging: batch, f4-slot

    const unsigned int* __restrict__ cp =
        hcnt + ((size_t)dir * 16 + (g & 15)) * 16;   // 8 member counters (64B row)
    unsigned int* __restrict__ mycnt =
        hcnt + ((size_t)dir * 16 + (g & 15)) * 16 + w;

    const uint2* __restrict__ G2 = (const uint2*)Gin;   // 4 gates fp16 / unit
    const size_t gbase = (size_t)dir * CT * 16384
                       + (size_t)(bbase + bloc) * 256 + ebase + e2sel;
    uint2 gv = G2[gbase];                     // t_local = 0

    __syncthreads();                          // weights staged

    for (int t = t0; t < t0 + CT; t++) {
        const int wslot = t & 1;

        // prefetch Gin for t+1 (overlaps the poll)
        int tln = t + 1 - t0; if (tln >= CT) tln = CT - 1;
        const uint2 gvn = G2[gbase + (size_t)tln * 16384];

        // ---- stage h(t-1): counter gate, then single payload read ----
        {
            uint2 hp2;
            if (t == 0) {
                float4 hv = ((const float4*)(h0
                    + ((size_t)dir * BATCH + bbase + sb) * HID))[k4];
                hp2.x = __builtin_bit_cast(unsigned int,
                            (h2){(_Float16)hv.x, (_Float16)hv.y});
                hp2.y = __builtin_bit_cast(unsigned int,
                            (h2){(_Float16)hv.z, (_Float16)hv.w});
            } else {
                const unsigned int tgt = 4u * (unsigned int)t;
                for (;;) {
                    uint4 c0 = poll_load16(cp);
                    uint4 c1 = poll_load16(cp + 4);
                    if ((c0.x >= tgt) & (c0.y >= tgt) & (c0.z >= tgt) & (c0.w >= tgt) &
                        (c1.x >= tgt) & (c1.y >= tgt) & (c1.z >= tgt) & (c1.w >= tgt))
                        break;
                    __builtin_amdgcn_s_sleep(1);
                }
                const unsigned int* dp = hdat
                    + ((((size_t)((t - 1) & 1) * 2 + dir) * BATCH + bbase + sb) * HID
                       + 4 * k4);
                uint4 v = poll_load16(dp);    // payload = fp16 in low 16 bits
                hp2.x = (v.x & 0xFFFFu) | (v.y << 16);
                hp2.y = (v.z & 0xFFFFu) | (v.w << 16);
            }
            *(uint2*)&Hd[wslot][sb][2 * k4] = hp2;
        }
        __syncthreads();

        // ---- fp16 dot2 GEMV: 8 rows x 4 batches x 16 k ----
        float a[2][4][4];
#pragma unroll
        for (int e2 = 0; e2 < 2; e2++)
#pragma unroll
            for (int q = 0; q < 4; q++)
#pragma unroll
                for (int b = 0; b < 4; b++) a[e2][q][b] = 0.f;

#pragma unroll
        for (int i2 = 0; i2 < 2; i2++) {
            const int co = 8 * ks + 4 * i2;
            uint4 h4[4];
#pragma unroll
            for (int b = 0; b < 4; b++)
                h4[b] = *(const uint4*)&Hd[wslot][b][co];
#pragma unroll
            for (int e2 = 0; e2 < 2; e2++)
#pragma unroll
                for (int q = 0; q < 4; q++) {
                    const uint4 w4 =
                        *(const uint4*)&Wl[wbase + ((e2 * 4 + q) * 2 + i2) * 4];
#pragma unroll
                    for (int b = 0; b < 4; b++) {
                        a[e2][q][b] = dot2_f16(w4.x, h4[b].x, a[e2][q][b]);
                        a[e2][q][b] = dot2_f16(w4.y, h4[b].y, a[e2][q][b]);
                        a[e2][q][b] = dot2_f16(w4.z, h4[b].z, a[e2][q][b]);
                        a[e2][q][b] = dot2_f16(w4.w, h4[b].w, a[e2][q][b]);
                    }
                }
        }

        // ---- reduce-scatter over lane^{1,2,4,8} ----
        float gfin[4];
#pragma unroll
        for (int q = 0; q < 4; q++) {
            float m[2][2];
#pragma unroll
            for (int e2 = 0; e2 < 2; e2++) {
                float s01 = P0 ? a[e2][q][0] : a[e2][q][1];
                float s23 = P0 ? a[e2][q][2] : a[e2][q][3];
                m[e2][0] = (P0 ? a[e2][q][1] : a[e2][q][0]) + __shfl_xor(s01, 1, 64);
                m[e2][1] = (P0 ? a[e2][q][3] : a[e2][q][2]) + __shfl_xor(s23, 1, 64);
            }
            float gq[2];
#pragma unroll
            for (int e2 = 0; e2 < 2; e2++) {
                float s = P1 ? m[e2][0] : m[e2][1];
                gq[e2] = (P1 ? m[e2][1] : m[e2][0]) + __shfl_xor(s, 2, 64);
            }
            float s = P2 ? gq[0] : gq[1];
            float gk = (P2 ? gq[1] : gq[0]) + __shfl_xor(s, 4, 64);
            gk += __shfl_xor(gk, 8, 64);
            gfin[q] = gk;
        }

        // ---- cell update for (ee = ebase+e2sel, b = bbase+bloc) ----
        const h2 g01 = __builtin_bit_cast(h2, gv.x);
        const h2 g23 = __builtin_bit_cast(h2, gv.y);
        const float x0 = gfin[0] + (float)g01.x;   // i
        const float x1 = gfin[1] + (float)g01.y;   // f
        const float x2 = gfin[2] + (float)g23.x;   // g
        const float x3 = gfin[3] + (float)g23.y;   // o
        c = fast_sig(x1) * c + fast_sig(x0) * fast_tanh(x2);
        const float h = fast_sig(x3) * fast_tanh(c);
        gv = gvn;

        // ---- publish: payload store, wave drain, counter bump ----
        if (ks < 8) {
            const int ee = ebase + e2sel;
            const int t_orig = dir ? (LSEQ - 1 - t) : t;
            const unsigned int pkt =
                (unsigned int)__builtin_bit_cast(u16, (_Float16)h);
            __hip_atomic_store(
                &hdat[(((size_t)wslot * 2 + dir) * BATCH + bbase + bloc) * HID + ee],
                pkt, __ATOMIC_RELAXED, __HIP_MEMORY_SCOPE_AGENT);
            hs[((size_t)(dir * LSEQ + t_orig) * BATCH + bbase + bloc) * HID + ee] = h;
        }
        asm volatile("s_waitcnt vmcnt(0)" ::: "memory");   // wave-wide retire
        if ((tid & 63) == 0)
            __hip_atomic_fetch_add(mycnt, 1u,
                __ATOMIC_RELAXED, __HIP_MEMORY_SCOPE_AGENT);
    }
    if (ks < 8)
        cbuf[((size_t)dir * BATCH + bbase + bloc) * HID + ebase + e2sel] = c;
}

// ---------------- output projection: logits[b][t][11] ----------------
__global__ void __launch_bounds__(256) logits_k(
    const float* __restrict__ hs, const float* __restrict__ Wout,
    const float* __restrict__ bout, float* __restrict__ logits)
{
    const int tid = threadIdx.x;
    const int rt = tid >> 4, tg = tid & 15;
    __shared__ float hrow[16][516];
    __shared__ float Wl[NTAG][516];
    const int rbase = blockIdx.x * 16;

#pragma unroll
    for (int i = 0; i < 8; i++) {
        int u  = tid + i * 256;
        int rr = u >> 7, c4 = u & 127;
        int r_g = rbase + rr;
        int b = r_g >> 9, t = r_g & 511;
        int d = (c4 >= 64) ? 1 : 0, k4 = c4 & 63;
        float4 hv = ((const float4*)hs)[(((size_t)d * LSEQ + t) * BATCH + b) * 64 + k4];
        *(float4*)&hrow[rr][c4 * 4] = hv;
    }
    for (int u = tid; u < NTAG * 128; u += 256) {
        int row = u >> 7, c4 = u & 127;
        float4 wv = ((const float4*)Wout)[(size_t)row * 128 + c4];
        *(float4*)&Wl[row][c4 * 4] = wv;
    }
    __syncthreads();

    if (tg < NTAG) {
        const float4* hp = (const float4*)&hrow[rt][0];
        const float4* wp = (const float4*)&Wl[tg][0];
        float acc = 0.f;
#pragma unroll 4
        for (int k = 0; k < 128; k++) {
            float4 h = hp[k], ww = wp[k];
            acc = fmaf(h.x, ww.x, acc); acc = fmaf(h.y, ww.y, acc);
            acc = fmaf(h.z, ww.z, acc); acc = fmaf(h.w, ww.w, acc);
        }
        int r_g = rbase + rt;
        logits[(size_t)r_g * NTAG + tg] = acc + bout[tg];
    }
}

// ---------------- Viterbi (one wave per batch element) ----------------
__global__ void __launch_bounds__(64) viterbi_k(
    const float* __restrict__ logits, const float* __restrict__ trans,
    float* __restrict__ out)
{
    const int b = blockIdx.x, lane = threadIdx.x;
    __shared__ float lgl[LSEQ * NTAG];
    __shared__ unsigned char bp[LSEQ][16];
    __shared__ float pathf[LSEQ];

    {
        const float4* src = (const float4*)(logits + (size_t)b * LSEQ * NTAG);
        float4* dst = (float4*)lgl;
        for (int u = lane; u < (LSEQ * NTAG) / 4; u += 64) dst[u] = src[u];
    }
    float tcol[NTAG];
    if (lane < NTAG) {
#pragma unroll
        for (int i = 0; i < NTAG; i++) tcol[i] = trans[i * NTAG + lane];
    }
    __syncthreads();

    float v = (lane < NTAG) ? lgl[lane] : -1e30f;
    for (int t = 1; t < LSEQ; t++) {
        float best = -1e30f; int bi = 0;
#pragma unroll
        for (int i = 0; i < NTAG; i++) {
            float vi = __shfl(v, i, 64) + tcol[i];
            if (vi > best) { best = vi; bi = i; }   // strict > == first-max
        }
        if (lane < NTAG) {
            v = lgl[t * NTAG + lane] + best;
            bp[t][lane] = (unsigned char)bi;
        }
    }
    float bestv = -1e30f; int bestj = 0;
#pragma unroll
    for (int j = 0; j < NTAG; j++) {
        float vj = __shfl(v, j, 64);
        if (vj > bestv) { bestv = vj; bestj = j; }
    }
    if (lane == 0) {
        out[b] = bestv;
        int st = bestj;
        pathf[LSEQ - 1] = (float)st;
        for (int t = LSEQ - 1; t >= 1; t--) { st = bp[t][st]; pathf[t - 1] = (float)st; }
    }
    __syncthreads();
    for (int t = lane; t < LSEQ; t += 64)
        out[BATCH + (size_t)b * LSEQ + t] = pathf[t];
}

// ---------------- host ----------------
extern "C" void kernel_launch(void* const* d_in, const int* in_sizes, int n_in,
                              void* d_out, int out_size, void* d_ws, size_t ws_size,
                              hipStream_t stream)
{
    (void)in_sizes; (void)n_in; (void)out_size;
    const int*   sent  = (const int*)  d_in[0];
    const float* emb   = (const float*)d_in[1];
    const float* Wihf  = (const float*)d_in[2];
    const float* Whhf  = (const float*)d_in[3];
    const float* bf    = (const float*)d_in[4];
    const float* Wihb  = (const float*)d_in[5];
    const float* Whhb  = (const float*)d_in[6];
    const float* bb    = (const float*)d_in[7];
    const float* Wout  = (const float*)d_in[8];
    const float* bout  = (const float*)d_in[9];
    const float* trans = (const float*)d_in[10];
    const float* h0    = (const float*)d_in[11];
    const float* c0    = (const float*)d_in[12];
    float* out = (float*)d_out;

    // ws (floats): Gin16[CT*65536] | hs[16777216] | hdat+hcnt[262144]
    //  | cbuf[32768] | logits[360448] | embb[4096000] | w16f[131072]
    //  | w16b[131072] | whh16f[131072] | whh16b[131072]
    const size_t fixed = 16777216ull + 262144ull + 32768ull + 360448ull
                       + 4096000ull + 131072ull + 131072ull
                       + 131072ull + 131072ull;
    int CT = LSEQ;
    while (CT > 8 && ((size_t)CT * 65536ull + fixed) * 4ull > ws_size) CT >>= 1;

    float* ws = (float*)d_ws;
    size_t off = 0;
    u16* Gin = (u16*)(ws + off); off += (size_t)CT * 65536ull;
    float* hs   = ws + off; off += 16777216ull;
    unsigned int* hdat = (unsigned int*)(ws + off);          // 65,536 u32
    unsigned int* hcnt = (unsigned int*)(ws + off) + 65536;  // 32x16 u32
    off += 262144ull;
    float* cbuf = ws + off; off += 32768ull;
    float* lgts = ws + off; off += 360448ull;
    u16* embb = (u16*)(ws + off); off += 4096000ull;
    u16* w16f = (u16*)(ws + off); off += 131072ull;
    u16* w16b = (u16*)(ws + off); off += 131072ull;
    u16* whh16f = (u16*)(ws + off); off += 131072ull;
    u16* whh16b = (u16*)(ws + off); off += 131072ull;

    hipMemsetAsync(hcnt, 0, 32 * 16 * sizeof(unsigned int), stream);

    hipLaunchKernelGGL(cvt_bf16, dim3(2048), dim3(256), 0, stream,
                       emb, embb, (32000 * 256) / 4);
    hipLaunchKernelGGL(cvt_bf16, dim3(256), dim3(256), 0, stream,
                       Wihf, w16f, (1024 * 256) / 4);
    hipLaunchKernelGGL(cvt_bf16, dim3(256), dim3(256), 0, stream,
                       Wihb, w16b, (1024 * 256) / 4);
    hipLaunchKernelGGL(cvt_f16, dim3(256), dim3(256), 0, stream,
                       Whhf, whh16f, (1024 * 256) / 4);
    hipLaunchKernelGGL(cvt_f16, dim3(256), dim3(256), 0, stream,
                       Whhb, whh16b, (1024 * 256) / 4);

    const int nch = LSEQ / CT;
    for (int c = 0; c < nch; c++) {
        int t0 = c * CT;
        hipLaunchKernelGGL(gemm_in, dim3(CT / 2, 8, 2), dim3(256), 0, stream,
                           sent, embb, w16f, w16b, bf, bb, Gin, t0, CT);
        hipLaunchKernelGGL(lstm_rec, dim3(256), dim3(256), 0, stream,
                           Gin, whh16f, whh16b, h0, c0, hs, hdat, hcnt, cbuf,
                           t0, CT);
    }
    hipLaunchKernelGGL(logits_k, dim3((BATCH * LSEQ) / 16), dim3(256), 0, stream,
                       hs, Wout, bout, lgts);
    hipLaunchKernelGGL(viterbi_k, dim3(BATCH), dim3(64), 0, stream,
                       lgts, trans, out);
}

// Round 12
// 1532.308 us; speedup vs baseline: 1.3419x; 1.3419x over previous
//
#include <hip/hip_runtime.h>
#include <cstdint>
#include <cstddef>
#include <cstring>

#define LSEQ 512
#define BATCH 64
#define DIM 256
#define HID 256
#define NTAG 11

typedef float vf4 __attribute__((ext_vector_type(4)));
typedef __bf16 bf16x8 __attribute__((ext_vector_type(8)));
typedef float f32x4 __attribute__((ext_vector_type(4)));
typedef _Float16 h2 __attribute__((ext_vector_type(2)));
typedef unsigned short u16;

static __device__ __forceinline__ float dot2_f16(unsigned int w, unsigned int h, float acc)
{
#if __has_builtin(__builtin_amdgcn_fdot2)
    return __builtin_amdgcn_fdot2(__builtin_bit_cast(h2, w),
                                  __builtin_bit_cast(h2, h), acc, false);
#else
    h2 a = __builtin_bit_cast(h2, w), b = __builtin_bit_cast(h2, h);
    acc = fmaf((float)a.x, (float)b.x, acc);
    return fmaf((float)a.y, (float)b.y, acc);
#endif
}

// Fast transcendentals on the serial critical path (r10: -118us verified).
static __device__ __forceinline__ float fast_sig(float x)
{
#if __has_builtin(__builtin_amdgcn_exp2f) && __has_builtin(__builtin_amdgcn_rcpf)
    return __builtin_amdgcn_rcpf(1.f + __builtin_amdgcn_exp2f(x * -1.442695041f));
#else
    return 1.f / (1.f + expf(-x));
#endif
}
static __device__ __forceinline__ float fast_tanh(float x)
{
#if __has_builtin(__builtin_amdgcn_exp2f) && __has_builtin(__builtin_amdgcn_rcpf)
    return 1.f - 2.f * __builtin_amdgcn_rcpf(__builtin_amdgcn_exp2f(x * 2.885390082f) + 1.f);
#else
    return tanhf(x);
#endif
}

// 16B coherent poll load: bypasses L1/L2 (sc0 sc1) so remote XCD publishes
// are visible; single request replaces 4x8B atomic loads.
static __device__ __forceinline__ uint4 poll_load16(const unsigned int* p)
{
    uint4 v;
    asm volatile("global_load_dwordx4 %0, %1, off sc0 sc1\n"
                 "s_waitcnt vmcnt(0)"
                 : "=&v"(v) : "v"(p) : "memory");
    return v;
}

// ---------------- fp32 -> bf16 (RNE) convert ----------------
__global__ void __launch_bounds__(256) cvt_bf16(
    const float* __restrict__ src, u16* __restrict__ dst, int n4)
{
    int i = blockIdx.x * blockDim.x + threadIdx.x;
    const int stride = gridDim.x * blockDim.x;
    for (; i < n4; i += stride) {
        float4 f = ((const float4*)src)[i];
        ushort4 r;
        unsigned int u;
        u = __float_as_uint(f.x); u += 0x7FFFu + ((u >> 16) & 1u); r.x = (u16)(u >> 16);
        u = __float_as_uint(f.y); u += 0x7FFFu + ((u >> 16) & 1u); r.y = (u16)(u >> 16);
        u = __float_as_uint(f.z); u += 0x7FFFu + ((u >> 16) & 1u); r.z = (u16)(u >> 16);
        u = __float_as_uint(f.w); u += 0x7FFFu + ((u >> 16) & 1u); r.w = (u16)(u >> 16);
        ((ushort4*)dst)[i] = r;
    }
}

// ---------------- fp32 -> fp16 (RNE) convert ----------------
__global__ void __launch_bounds__(256) cvt_f16(
    const float* __restrict__ src, u16* __restrict__ dst, int n4)
{
    int i = blockIdx.x * blockDim.x + threadIdx.x;
    const int stride = gridDim.x * blockDim.x;
    for (; i < n4; i += stride) {
        float4 f = ((const float4*)src)[i];
        ushort4 r;
        r.x = __builtin_bit_cast(u16, (_Float16)f.x);
        r.y = __builtin_bit_cast(u16, (_Float16)f.y);
        r.z = __builtin_bit_cast(u16, (_Float16)f.z);
        r.w = __builtin_bit_cast(u16, (_Float16)f.w);
        ((ushort4*)dst)[i] = r;
    }
}

// ---------------- input GEMM via bf16 MFMA (+gather, +bias) ----------------
// r12: register->LDS DOUBLE-BUFFER on the proven 32-wide-chunk pitch-40
// structure (r11's full-K 135KB variant dropped occupancy to 1 WG/CU and
// regressed).  One barrier per chunk (8 total, was 16); next-chunk global
// loads issue BEFORE the MFMAs so HBM/L3 latency hides under compute.
// Race audit: body = {loads(k+1)->regs; ds_read buf[cur]; MFMA;
// ds_write->buf[nxt]; barrier} — write(k+1) vs read(k+1) separated by the
// end-of-body barrier; read(k) vs overwrite(k+2) likewise.  LDS 40KB ->
// 4 WGs/CU.  Epilogue (gate-contiguous fp16 Gin) unchanged:
//   u16 index (((dir*CT + tl)*64 + b)*256 + e)*4 + q    (n = q*256 + e)
__global__ void __launch_bounds__(256) gemm_in(
    const int* __restrict__ sent, const u16* __restrict__ embb,
    const u16* __restrict__ w16f, const u16* __restrict__ w16b,
    const float* __restrict__ bf_, const float* __restrict__ bb_,
    u16* __restrict__ Gin, int t0, int CT)
{
    const int mtile = blockIdx.x, ntile = blockIdx.y, dir = blockIdx.z;
    const u16* __restrict__ W16 = dir ? w16b : w16f;
    const float* __restrict__ bias = dir ? bb_ : bf_;
    const int tid = threadIdx.x;
    const int wave = tid >> 6, lane = tid & 63;
    const int wm = wave & 1, wn = wave >> 1;

    __shared__ u16 Asm[2][128][40];   // [buf][m][k-chunk] pitch 40
    __shared__ u16 Bsm[2][128][40];   // [buf][n][k-chunk]

    // staging: thread -> (row = tid>>1, half = tid&1), 32B per matrix/chunk
    const int row = tid >> 1, half = tid & 1;
    const u16* ap;
    {
        int m_g = mtile * 128 + row;
        int tl = m_g >> 6, b = m_g & 63;
        int tg = t0 + tl;
        int tt = dir ? (LSEQ - 1 - tg) : tg;
        ap = embb + (size_t)sent[b * LSEQ + tt] * DIM;
    }
    const u16* bp = W16 + (size_t)(ntile * 128 + row) * DIM;

    // preload chunk 0 into buf 0
    {
        *(uint4*)&Asm[0][row][half * 16 + 0] = *(const uint4*)(ap + half * 16);
        *(uint4*)&Asm[0][row][half * 16 + 8] = *(const uint4*)(ap + half * 16 + 8);
        *(uint4*)&Bsm[0][row][half * 16 + 0] = *(const uint4*)(bp + half * 16);
        *(uint4*)&Bsm[0][row][half * 16 + 8] = *(const uint4*)(bp + half * 16 + 8);
    }
    __syncthreads();

    f32x4 acc[4][4];
#pragma unroll
    for (int i = 0; i < 4; i++)
#pragma unroll
        for (int j = 0; j < 4; j++) acc[i][j] = (f32x4){0.f, 0.f, 0.f, 0.f};

    const int col = lane & 15, quad = lane >> 4;

#pragma unroll
    for (int ki = 0; ki < 8; ki++) {
        const int cur = ki & 1, nxt = cur ^ 1;

        // issue next-chunk global loads first (hide under MFMA)
        uint4 na0, na1, nb0, nb1;
        if (ki < 7) {
            const int k0 = (ki + 1) * 32;
            na0 = *(const uint4*)(ap + k0 + half * 16);
            na1 = *(const uint4*)(ap + k0 + half * 16 + 8);
            nb0 = *(const uint4*)(bp + k0 + half * 16);
            nb1 = *(const uint4*)(bp + k0 + half * 16 + 8);
        }

        bf16x8 af[4], bg[4];
#pragma unroll
        for (int i = 0; i < 4; i++) {
            af[i] = *(const bf16x8*)&Asm[cur][wm * 64 + i * 16 + col][quad * 8];
            bg[i] = *(const bf16x8*)&Bsm[cur][wn * 64 + i * 16 + col][quad * 8];
        }
#pragma unroll
        for (int mt = 0; mt < 4; mt++)
#pragma unroll
            for (int nt = 0; nt < 4; nt++)
                acc[mt][nt] = __builtin_amdgcn_mfma_f32_16x16x32_bf16(
                    af[mt], bg[nt], acc[mt][nt], 0, 0, 0);

        if (ki < 7) {
            *(uint4*)&Asm[nxt][row][half * 16 + 0] = na0;
            *(uint4*)&Asm[nxt][row][half * 16 + 8] = na1;
            *(uint4*)&Bsm[nxt][row][half * 16 + 0] = nb0;
            *(uint4*)&Bsm[nxt][row][half * 16 + 8] = nb1;
        }
        __syncthreads();
    }

#pragma unroll
    for (int nt = 0; nt < 4; nt++) {
        const int n_g = ntile * 128 + wn * 64 + nt * 16 + col;
        const float bv = bias[n_g];
        const int q = n_g >> 8, e = n_g & 255;
#pragma unroll
        for (int mt = 0; mt < 4; mt++)
#pragma unroll
            for (int r = 0; r < 4; r++) {
                const int m_g = mtile * 128 + wm * 64 + mt * 16 + quad * 4 + r;
                const int tl = m_g >> 6, b = m_g & 63;
                Gin[(((size_t)(dir * CT + tl) * 64 + b) * 256 + e) * 4 + q]
                    = __builtin_bit_cast(u16, (_Float16)(acc[mt][nt][r] + bv));
            }
    }
}

// ---------------- persistent bidirectional LSTM recurrence ------
// r12: REVERT to the r10 champion (1186us verified).  r11's counter-gated
// exchange was refuted (+460us): it split the single-RT tag-in-data
// consume into TWO serialized RTs (counter discovery, then payload) and
// its publish-side vmcnt(0) drain also stalled on the Gin prefetch.
// Exchange design space now scanned: M in {4,8,16} (8 minimal),
// congestion cuts (win: 32-bit packed word + dwordx4 poll + CT=512),
// counter-gate (loss).  Chain sits at ~2 L3-RTs + compute per step.
// Structure: 256 WGs = 32 groups x 8 members; 32-bit packed exchange word
// (t+1)<<16 | fp16(h); poll = one dwordx4 sc0 sc1; fp16 Gin CT=512;
// weights in thread-private LDS blocks (pitch 65, free 2-way);
// reduce-scatter over lane^{1,2,4,8}; fast_sig/fast_tanh cell.
__global__ void __launch_bounds__(256, 1) lstm_rec(
    const u16* __restrict__ Gin,
    const u16* __restrict__ Whh16f, const u16* __restrict__ Whh16b,
    const float* __restrict__ h0, const float* __restrict__ c0,
    float* __restrict__ hs, unsigned int* __restrict__ htag,
    float* __restrict__ cbuf, int t0, int CT)
{
    const int wg = blockIdx.x;
    const int w = wg >> 5, g = wg & 31;
    const int dir   = g >> 4;
    const int bbase = (g & 15) << 2;
    const int tid = threadIdx.x;
    const int ks = tid & 15;            // k-slice index (16 halves = 8 dwords)
    const int ep = tid >> 4;            // ee-pair index 0..15
    const int ebase = w * 32 + ep * 2;  // first of the 2 hidden elems
    const int P0 = ks & 1, P1 = (ks >> 1) & 1, P2 = (ks >> 2) & 1;
    const int bloc = ks & 3;            // batch slot this thread finalizes
    const int e2sel = P2;               // which of its 2 elems it finalizes
    const u16* __restrict__ Whh16 = dir ? Whh16b : Whh16f;

    __shared__ unsigned int Wl[256 * 65];        // 66,560 B private blocks
    __shared__ unsigned int Hd[2][4][132];       // fp16-pair h, 4,224 B

    const int wbase = tid * 65;

    // ---- one-time weight stage into thread-private LDS block ----
#pragma unroll
    for (int e2 = 0; e2 < 2; e2++)
#pragma unroll
        for (int q = 0; q < 4; q++) {
            const unsigned int* wp =
                (const unsigned int*)(Whh16 + (size_t)(q * 256 + ebase + e2) * HID);
#pragma unroll
            for (int j = 0; j < 2; j++) {
                *(uint4*)&Wl[wbase + ((e2 * 4 + q) * 2 + j) * 4] =
                    *(const uint4*)(wp + 8 * ks + 4 * j);
            }
        }

    float c = ((t0 == 0) ? c0 : cbuf)
        [((size_t)dir * BATCH + bbase + bloc) * HID + ebase + e2sel];

    const int sb = tid >> 6, k4 = tid & 63;   // staging: batch, f4-slot

    const uint2* __restrict__ G2 = (const uint2*)Gin;   // 4 gates fp16 / unit
    const size_t gbase = (size_t)dir * CT * 16384
                       + (size_t)(bbase + bloc) * 256 + ebase + e2sel;
    uint2 gv = G2[gbase];                     // t_local = 0

    __syncthreads();                          // weights staged

    for (int t = t0; t < t0 + CT; t++) {
        const int wslot = t & 1;

        // prefetch Gin for t+1 (overlaps the poll)
        int tln = t + 1 - t0; if (tln >= CT) tln = CT - 1;
        const uint2 gvn = G2[gbase + (size_t)tln * 16384];

        // ---- stage h(t-1): poll packed tag16|h16 words, write LDS ----
        {
            uint2 hp2;
            if (t == 0) {
                float4 hv = ((const float4*)(h0
                    + ((size_t)dir * BATCH + bbase + sb) * HID))[k4];
                hp2.x = __builtin_bit_cast(unsigned int,
                            (h2){(_Float16)hv.x, (_Float16)hv.y});
                hp2.y = __builtin_bit_cast(unsigned int,
                            (h2){(_Float16)hv.z, (_Float16)hv.w});
            } else {
                const unsigned int* hp =
                    htag + ((((size_t)((t - 1) & 1) * 2 + dir) * BATCH + bbase + sb) * HID
                            + 4 * k4);
                const unsigned int tg = (unsigned int)t;
                uint4 v;
                for (;;) {
                    v = poll_load16(hp);
                    if (((v.x >> 16) == tg) & ((v.y >> 16) == tg) &
                        ((v.z >> 16) == tg) & ((v.w >> 16) == tg))
                        break;
                    __builtin_amdgcn_s_sleep(1);
                }
                hp2.x = (v.x & 0xFFFFu) | (v.y << 16);
                hp2.y = (v.z & 0xFFFFu) | (v.w << 16);
            }
            *(uint2*)&Hd[wslot][sb][2 * k4] = hp2;
        }
        __syncthreads();

        // ---- fp16 dot2 GEMV: 8 rows x 4 batches x 16 k ----
        float a[2][4][4];
#pragma unroll
        for (int e2 = 0; e2 < 2; e2++)
#pragma unroll
            for (int q = 0; q < 4; q++)
#pragma unroll
                for (int b = 0; b < 4; b++) a[e2][q][b] = 0.f;

#pragma unroll
        for (int i2 = 0; i2 < 2; i2++) {
            const int co = 8 * ks + 4 * i2;
            uint4 h4[4];
#pragma unroll
            for (int b = 0; b < 4; b++)
                h4[b] = *(const uint4*)&Hd[wslot][b][co];
#pragma unroll
            for (int e2 = 0; e2 < 2; e2++)
#pragma unroll
                for (int q = 0; q < 4; q++) {
                    const uint4 w4 =
                        *(const uint4*)&Wl[wbase + ((e2 * 4 + q) * 2 + i2) * 4];
#pragma unroll
                    for (int b = 0; b < 4; b++) {
                        a[e2][q][b] = dot2_f16(w4.x, h4[b].x, a[e2][q][b]);
                        a[e2][q][b] = dot2_f16(w4.y, h4[b].y, a[e2][q][b]);
                        a[e2][q][b] = dot2_f16(w4.z, h4[b].z, a[e2][q][b]);
                        a[e2][q][b] = dot2_f16(w4.w, h4[b].w, a[e2][q][b]);
                    }
                }
        }

        // ---- reduce-scatter over lane^{1,2,4,8} ----
        float gfin[4];
#pragma unroll
        for (int q = 0; q < 4; q++) {
            float m[2][2];
#pragma unroll
            for (int e2 = 0; e2 < 2; e2++) {
                float s01 = P0 ? a[e2][q][0] : a[e2][q][1];
                float s23 = P0 ? a[e2][q][2] : a[e2][q][3];
                m[e2][0] = (P0 ? a[e2][q][1] : a[e2][q][0]) + __shfl_xor(s01, 1, 64);
                m[e2][1] = (P0 ? a[e2][q][3] : a[e2][q][2]) + __shfl_xor(s23, 1, 64);
            }
            float gq[2];
#pragma unroll
            for (int e2 = 0; e2 < 2; e2++) {
                float s = P1 ? m[e2][0] : m[e2][1];
                gq[e2] = (P1 ? m[e2][1] : m[e2][0]) + __shfl_xor(s, 2, 64);
            }
            float s = P2 ? gq[0] : gq[1];
            float gk = (P2 ? gq[1] : gq[0]) + __shfl_xor(s, 4, 64);
            gk += __shfl_xor(gk, 8, 64);
            gfin[q] = gk;
        }

        // ---- cell update for (ee = ebase+e2sel, b = bbase+bloc) ----
        const h2 g01 = __builtin_bit_cast(h2, gv.x);
        const h2 g23 = __builtin_bit_cast(h2, gv.y);
        const float x0 = gfin[0] + (float)g01.x;   // i
        const float x1 = gfin[1] + (float)g01.y;   // f
        const float x2 = gfin[2] + (float)g23.x;   // g
        const float x3 = gfin[3] + (float)g23.y;   // o
        c = fast_sig(x1) * c + fast_sig(x0) * fast_tanh(x2);
        const float h = fast_sig(x3) * fast_tanh(c);
        gv = gvn;

        if (ks < 8) {
            const int ee = ebase + e2sel;
            const int t_orig = dir ? (LSEQ - 1 - t) : t;
            const unsigned int pkt =
                ((unsigned int)(t + 1) << 16)
                | (unsigned int)__builtin_bit_cast(u16, (_Float16)h);
            __hip_atomic_store(
                &htag[(((size_t)wslot * 2 + dir) * BATCH + bbase + bloc) * HID + ee],
                pkt, __ATOMIC_RELAXED, __HIP_MEMORY_SCOPE_AGENT);
            hs[((size_t)(dir * LSEQ + t_orig) * BATCH + bbase + bloc) * HID + ee] = h;
        }
    }
    if (ks < 8)
        cbuf[((size_t)dir * BATCH + bbase + bloc) * HID + ebase + e2sel] = c;
}

// ---------------- output projection: logits[b][t][11] ----------------
__global__ void __launch_bounds__(256) logits_k(
    const float* __restrict__ hs, const float* __restrict__ Wout,
    const float* __restrict__ bout, float* __restrict__ logits)
{
    const int tid = threadIdx.x;
    const int rt = tid >> 4, tg = tid & 15;
    __shared__ float hrow[16][516];
    __shared__ float Wl[NTAG][516];
    const int rbase = blockIdx.x * 16;

#pragma unroll
    for (int i = 0; i < 8; i++) {
        int u  = tid + i * 256;
        int rr = u >> 7, c4 = u & 127;
        int r_g = rbase + rr;
        int b = r_g >> 9, t = r_g & 511;
        int d = (c4 >= 64) ? 1 : 0, k4 = c4 & 63;
        float4 hv = ((const float4*)hs)[(((size_t)d * LSEQ + t) * BATCH + b) * 64 + k4];
        *(float4*)&hrow[rr][c4 * 4] = hv;
    }
    for (int u = tid; u < NTAG * 128; u += 256) {
        int row = u >> 7, c4 = u & 127;
        float4 wv = ((const float4*)Wout)[(size_t)row * 128 + c4];
        *(float4*)&Wl[row][c4 * 4] = wv;
    }
    __syncthreads();

    if (tg < NTAG) {
        const float4* hp = (const float4*)&hrow[rt][0];
        const float4* wp = (const float4*)&Wl[tg][0];
        float acc = 0.f;
#pragma unroll 4
        for (int k = 0; k < 128; k++) {
            float4 h = hp[k], ww = wp[k];
            acc = fmaf(h.x, ww.x, acc); acc = fmaf(h.y, ww.y, acc);
            acc = fmaf(h.z, ww.z, acc); acc = fmaf(h.w, ww.w, acc);
        }
        int r_g = rbase + rt;
        logits[(size_t)r_g * NTAG + tg] = acc + bout[tg];
    }
}

// ---------------- Viterbi (one wave per batch element) ----------------
__global__ void __launch_bounds__(64) viterbi_k(
    const float* __restrict__ logits, const float* __restrict__ trans,
    float* __restrict__ out)
{
    const int b = blockIdx.x, lane = threadIdx.x;
    __shared__ float lgl[LSEQ * NTAG];
    __shared__ unsigned char bp[LSEQ][16];
    __shared__ float pathf[LSEQ];

    {
        const float4* src = (const float4*)(logits + (size_t)b * LSEQ * NTAG);
        float4* dst = (float4*)lgl;
        for (int u = lane; u < (LSEQ * NTAG) / 4; u += 64) dst[u] = src[u];
    }
    float tcol[NTAG];
    if (lane < NTAG) {
#pragma unroll
        for (int i = 0; i < NTAG; i++) tcol[i] = trans[i * NTAG + lane];
    }
    __syncthreads();

    float v = (lane < NTAG) ? lgl[lane] : -1e30f;
    for (int t = 1; t < LSEQ; t++) {
        float best = -1e30f; int bi = 0;
#pragma unroll
        for (int i = 0; i < NTAG; i++) {
            float vi = __shfl(v, i, 64) + tcol[i];
            if (vi > best) { best = vi; bi = i; }   // strict > == first-max
        }
        if (lane < NTAG) {
            v = lgl[t * NTAG + lane] + best;
            bp[t][lane] = (unsigned char)bi;
        }
    }
    float bestv = -1e30f; int bestj = 0;
#pragma unroll
    for (int j = 0; j < NTAG; j++) {
        float vj = __shfl(v, j, 64);
        if (vj > bestv) { bestv = vj; bestj = j; }
    }
    if (lane == 0) {
        out[b] = bestv;
        int st = bestj;
        pathf[LSEQ - 1] = (float)st;
        for (int t = LSEQ - 1; t >= 1; t--) { st = bp[t][st]; pathf[t - 1] = (float)st; }
    }
    __syncthreads();
    for (int t = lane; t < LSEQ; t += 64)
        out[BATCH + (size_t)b * LSEQ + t] = pathf[t];
}

// ---------------- host ----------------
extern "C" void kernel_launch(void* const* d_in, const int* in_sizes, int n_in,
                              void* d_out, int out_size, void* d_ws, size_t ws_size,
                              hipStream_t stream)
{
    (void)in_sizes; (void)n_in; (void)out_size;
    const int*   sent  = (const int*)  d_in[0];
    const float* emb   = (const float*)d_in[1];
    const float* Wihf  = (const float*)d_in[2];
    const float* Whhf  = (const float*)d_in[3];
    const float* bf    = (const float*)d_in[4];
    const float* Wihb  = (const float*)d_in[5];
    const float* Whhb  = (const float*)d_in[6];
    const float* bb    = (const float*)d_in[7];
    const float* Wout  = (const float*)d_in[8];
    const float* bout  = (const float*)d_in[9];
    const float* trans = (const float*)d_in[10];
    const float* h0    = (const float*)d_in[11];
    const float* c0    = (const float*)d_in[12];
    float* out = (float*)d_out;

    // ws (floats): Gin16[CT*65536] | hs[16777216] | htag[262144] | cbuf[32768]
    //  | logits[360448] | embb[4096000] | w16f[131072] | w16b[131072]
    //  | whh16f[131072] | whh16b[131072]
    const size_t fixed = 16777216ull + 262144ull + 32768ull + 360448ull
                       + 4096000ull + 131072ull + 131072ull
                       + 131072ull + 131072ull;
    int CT = LSEQ;
    while (CT > 8 && ((size_t)CT * 65536ull + fixed) * 4ull > ws_size) CT >>= 1;

    float* ws = (float*)d_ws;
    size_t off = 0;
    u16* Gin = (u16*)(ws + off); off += (size_t)CT * 65536ull;
    float* hs   = ws + off; off += 16777216ull;
    unsigned int* htag = (unsigned int*)(ws + off); off += 262144ull;
    float* cbuf = ws + off; off += 32768ull;
    float* lgts = ws + off; off += 360448ull;
    u16* embb = (u16*)(ws + off); off += 4096000ull;
    u16* w16f = (u16*)(ws + off); off += 131072ull;
    u16* w16b = (u16*)(ws + off); off += 131072ull;
    u16* whh16f = (u16*)(ws + off); off += 131072ull;
    u16* whh16b = (u16*)(ws + off); off += 131072ull;

    hipLaunchKernelGGL(cvt_bf16, dim3(2048), dim3(256), 0, stream,
                       emb, embb, (32000 * 256) / 4);
    hipLaunchKernelGGL(cvt_bf16, dim3(256), dim3(256), 0, stream,
                       Wihf, w16f, (1024 * 256) / 4);
    hipLaunchKernelGGL(cvt_bf16, dim3(256), dim3(256), 0, stream,
                       Wihb, w16b, (1024 * 256) / 4);
    hipLaunchKernelGGL(cvt_f16, dim3(256), dim3(256), 0, stream,
                       Whhf, whh16f, (1024 * 256) / 4);
    hipLaunchKernelGGL(cvt_f16, dim3(256), dim3(256), 0, stream,
                       Whhb, whh16b, (1024 * 256) / 4);

    const int nch = LSEQ / CT;
    for (int c = 0; c < nch; c++) {
        int t0 = c * CT;
        hipLaunchKernelGGL(gemm_in, dim3(CT / 2, 8, 2), dim3(256), 0, stream,
                           sent, embb, w16f, w16b, bf, bb, Gin, t0, CT);
        hipLaunchKernelGGL(lstm_rec, dim3(256), dim3(256), 0, stream,
                           Gin, whh16f, whh16b, h0, c0, hs, htag, cbuf, t0, CT);
    }
    hipLaunchKernelGGL(logits_k, dim3((BATCH * LSEQ) / 16), dim3(256), 0, stream,
                       hs, Wout, bout, lgts);
    hipLaunchKernelGGL(viterbi_k, dim3(BATCH), dim3(64), 0, stream,
                       lgts, trans, out);
}